// Round 4
// baseline (554662.207 us; speedup 1.0000x reference)
//
#include <hip/hip_runtime.h>
#include <math.h>

// Problem constants
#define B_   64
#define U_   1024
#define E_   512
#define D_   640
#define L4_  2560
#define TC   64          // time-chunk length
#define NCH  16          // number of chunks (TC*NCH == U_)
#define NBLK 160         // persistent blocks (4 d's each); 160 <= 256 CUs -> co-resident
#define SUBQ (NBLK / 8)  // blocks per sub-counter
#define KS_  8           // k-splits (waves) per block
#define KPT  80          // k's per thread (640 / 8)

// ---------------------------------------------------------------------------
// GEMM: C[t][n][b] = bias[n] + sum_k A[m][k] * W[k][n],  m = t*64 + b
// MODE 0: A row m comes from embed[targets[b][t0+t]] (gather), K = 512
// MODE 1: A is h0c with layout [t][k][b] (stride 640*64 per t),  K = 640
// Block tile 128x128, 256 threads, 8x8 per-thread tile, BK=8.  (unchanged)
// ---------------------------------------------------------------------------
template <int MODE>
__global__ __launch_bounds__(256) void gemm_kernel(
    const float* __restrict__ A,        // MODE0: embed [V][E]; MODE1: h0c [TC][640][64]
    const int*   __restrict__ targets,  // [B][U], used in MODE0
    const float* __restrict__ Wm,       // [K][2560]
    const float* __restrict__ bias,     // [2560]
    float* __restrict__ xz,             // [TC][2560][64]
    int K, int t0)
{
    const int tid = threadIdx.x;
    const int m0 = blockIdx.x * 128;
    const int n0 = blockIdx.y * 128;

    __shared__ float As[8][132];
    __shared__ float Bs[8][132];

    float acc[8][8];
#pragma unroll
    for (int i = 0; i < 8; ++i)
#pragma unroll
        for (int j = 0; j < 8; ++j) acc[i][j] = 0.f;

    const float* a_ptr;
    int a_ml = 0, a_kq = 0, a_k = 0;
    if (MODE == 0) {
        a_ml = tid & 127;
        a_kq = (tid >> 7) * 4;
        int m  = m0 + a_ml;
        int b  = m & 63;
        int tl = m >> 6;
        int idx = targets[b * U_ + t0 + tl];
        a_ptr = A + (size_t)idx * E_ + a_kq;
    } else {
        a_k  = tid >> 5;
        a_ml = (tid & 31) * 4;
        int m  = m0 + a_ml;
        int b  = m & 63;
        int tl = m >> 6;
        a_ptr = A + (size_t)tl * (D_ * 64) + (size_t)a_k * 64 + b;
    }
    const int b_k  = tid >> 5;
    const int b_n4 = (tid & 31) * 4;

    const int tx = tid & 15;
    const int ty = tid >> 4;

    for (int k0 = 0; k0 < K; k0 += 8) {
        if (MODE == 0) {
            float4 av = *(const float4*)(a_ptr + k0);
            As[a_kq + 0][a_ml] = av.x;
            As[a_kq + 1][a_ml] = av.y;
            As[a_kq + 2][a_ml] = av.z;
            As[a_kq + 3][a_ml] = av.w;
        } else {
            float4 av = *(const float4*)(a_ptr + (size_t)k0 * 64);
            *(float4*)&As[a_k][a_ml] = av;
        }
        {
            float4 bv = *(const float4*)(Wm + (size_t)(k0 + b_k) * L4_ + n0 + b_n4);
            *(float4*)&Bs[b_k][b_n4] = bv;
        }
        __syncthreads();

#pragma unroll
        for (int k = 0; k < 8; ++k) {
            float af[8], bf[8];
            *(float4*)&af[0] = *(const float4*)&As[k][ty * 8];
            *(float4*)&af[4] = *(const float4*)&As[k][ty * 8 + 4];
            *(float4*)&bf[0] = *(const float4*)&Bs[k][tx * 8];
            *(float4*)&bf[4] = *(const float4*)&Bs[k][tx * 8 + 4];
#pragma unroll
            for (int i = 0; i < 8; ++i)
#pragma unroll
                for (int j = 0; j < 8; ++j) acc[i][j] += af[i] * bf[j];
        }
        __syncthreads();
    }

#pragma unroll
    for (int i = 0; i < 8; ++i) {
        int m  = m0 + ty * 8 + i;
        int tl = m >> 6;
        int b  = m & 63;
        float* outp = xz + (size_t)tl * (L4_ * 64) + b;
#pragma unroll
        for (int j = 0; j < 8; ++j) {
            int n = n0 + tx * 8 + j;
            outp[(size_t)n * 64] = acc[i][j] + bias[n];
        }
    }
}

// ---------------------------------------------------------------------------
// Pre-transpose recurrent weights into per-block-group layout:
//   Upg[g][k][dd][gate] = Uw[k][gate*640 + (g*4+dd)],  g = d>>2, dd = d&3
// One block's slice (g fixed) is 640*16 floats = 40 KB, contiguous; the seq
// kernel streams it per step via WAVE-UNIFORM scalar loads (s_load from L2)
// -> feeds v_fmac_f32 v,s,v directly. NO per-lane broadcast traffic.
// ---------------------------------------------------------------------------
__global__ __launch_bounds__(256) void prep_up_kernel(
    const float* __restrict__ U0w, const float* __restrict__ U1w,
    float* __restrict__ Up0, float* __restrict__ Up1)
{
    const int k = blockIdx.x;                       // 0..639
    const float* Uw = blockIdx.y ? U1w : U0w;
    float*       Up = blockIdx.y ? Up1 : Up0;
    for (int d = threadIdx.x; d < D_; d += 256) {   // coalesced reads over d
        float4 v;
        v.x = Uw[(size_t)k * L4_ + d];
        v.y = Uw[(size_t)k * L4_ + 640  + d];
        v.z = Uw[(size_t)k * L4_ + 1280 + d];
        v.w = Uw[(size_t)k * L4_ + 1920 + d];
        *(float4*)(Up + ((((size_t)(d >> 2) * 640 + k) * 4) + (d & 3)) * 4) = v;
    }
}

// ---------------------------------------------------------------------------
// LLC-coherent scalar access helpers: relaxed agent-scope atomics compile to
// sc1-flagged global_load/store_dword -> bypass the non-coherent per-XCD L2,
// write-through/read-from LLC. Zero cache-maintenance instructions.
// ---------------------------------------------------------------------------
__device__ __forceinline__ float ldg_llc(const float* p) {
    return __hip_atomic_load(p, __ATOMIC_RELAXED, __HIP_MEMORY_SCOPE_AGENT);
}
__device__ __forceinline__ void stg_llc(float* p, float v) {
    __hip_atomic_store(p, v, __ATOMIC_RELAXED, __HIP_MEMORY_SCOPE_AGENT);
}

// ---------------------------------------------------------------------------
// Two-level, monotonic (no-reset) grid barrier. All counters relaxed.
// (Proven correct+fast in round 3; only poll sleep shortened 4->1 to cut
//  wakeup quantization now that per-step time target is ~2-3 us.)
// ---------------------------------------------------------------------------
__device__ __forceinline__ void grid_barrier(unsigned* bar, unsigned done)
{
    asm volatile("s_waitcnt vmcnt(0)" ::: "memory");
    __syncthreads();
    if (threadIdx.x == 0) {
        unsigned* sub    = bar + ((blockIdx.x & 7) << 5);   // 128B-separated lines
        unsigned* master = bar + (8 << 5);
        unsigned a = __hip_atomic_fetch_add(sub, 1u, __ATOMIC_RELAXED, __HIP_MEMORY_SCOPE_AGENT);
        if (a == done * SUBQ - 1u)
            __hip_atomic_fetch_add(master, 1u, __ATOMIC_RELAXED, __HIP_MEMORY_SCOPE_AGENT);
        const unsigned tgt = done * 8u;
        while (__hip_atomic_load(master, __ATOMIC_RELAXED, __HIP_MEMORY_SCOPE_AGENT) < tgt)
            __builtin_amdgcn_s_sleep(1);
    }
    __syncthreads();
}

// ---------------------------------------------------------------------------
// Persistent LSTM sequence kernel: TC=64 timesteps in ONE launch.
// Grid: 160 blocks x 512 threads (8 waves, 2/SIMD); block owns dims d0..d0+3.
// Wave ks (tid>>6) owns k-slice [ks*80, ks*80+80). Per step:
//   - h slice loaded into 80 REGISTERS per thread (sc1 LLC loads, all
//     independent -> fully pipelined);
//   - weights stream via wave-uniform s_load from L2-resident Upg slice and
//     feed v_fmac_f32 v,s,v (1 scalar read per VALU inst) -- this removes
//     the ds_read_b128 broadcast wall that capped round 3 at 12.5 us/step
//     (2560 b128 x 12cyc = 30.7k cyc/CU/step == measured; VALUBusy 18% == 
//     5120/30700 predicted by that model);
//   - 8 partials reduced through a 32 KB LDS array; epilogue on threads<256.
// c-state in registers across the whole chunk.
// ---------------------------------------------------------------------------
__global__ __launch_bounds__(512) void lstm_seq_kernel(
    const float* __restrict__ xz,      // [TC][2560][64]
    const float* __restrict__ Upg,     // [160][640][4][4] pre-transposed
    float* __restrict__ hA,            // [640][64] ping
    float* __restrict__ hB,            // [640][64] pong
    float* __restrict__ c_st,          // [640][64]
    const int* __restrict__ lens,      // [64]
    float* __restrict__ hc_out,        // [TC][640][64]
    int t0,
    unsigned* __restrict__ bar,
    unsigned bar_base)                 // absolute barrier index base for this launch
{
    const int tid = threadIdx.x;
    const int d0  = blockIdx.x * 4;
    const int b   = tid & 63;
    const int ks  = tid >> 6;            // 0..7
    const int kbeg = ks * KPT;

    __shared__ float red[128][64];       // 32 KB: [ (i=dd*4+gate)*8 + ks ][ b ]

    // wave-uniform weight stream base for this wave's k-slice
    const float* __restrict__ wk = Upg + (size_t)blockIdx.x * (640 * 16)
                                       + (size_t)kbeg * 16;

    // epilogue-private state: threads 0..255 own one (d,b) cell
    const bool epi = tid < 256;
    const int ed = d0 + ((tid >> 6) & 3);
    const int eb = tid & 63;
    float c_reg = 0.f;
    int   len_b = 0;
    if (epi) {
        c_reg = c_st[ed * 64 + eb];      // c never crosses blocks
        len_b = lens[eb];
    }

    for (int tl = 0; tl < TC; ++tl) {
        const int t = t0 + tl;
        const float* hp = (t & 1) ? hB : hA;    // same parity rule as before
        float*       hn = (t & 1) ? hA : hB;

        // prefetch epilogue operands early -> latency hidden under k-loop
        float xzv[4];
        float hp_epi = 0.f;
        if (epi) {
            const float* xzp = xz + (size_t)tl * (L4_ * 64) + eb;
#pragma unroll
            for (int g = 0; g < 4; ++g)
                xzv[g] = xzp[(size_t)(ed + 640 * g) * 64];
            hp_epi = ldg_llc(hp + ed * 64 + eb);
        }

        // load this wave's h slice into registers (80 independent LLC loads)
        float hv[KPT];
        const float* hpb = hp + (size_t)kbeg * 64 + b;
#pragma unroll
        for (int j = 0; j < KPT; ++j)
            hv[j] = ldg_llc(hpb + (j << 6));

        // pure-VALU FMA loop: p[i] += s_w * v_h  (weights via scalar pipe)
        float p[16];
#pragma unroll
        for (int i = 0; i < 16; ++i) p[i] = 0.f;
#pragma unroll
        for (int k = 0; k < KPT; ++k) {
            const float hvv = hv[k];
#pragma unroll
            for (int i = 0; i < 16; ++i)
                p[i] += wk[k * 16 + i] * hvv;
        }

#pragma unroll
        for (int i = 0; i < 16; ++i) red[(i << 3) | ks][b] = p[i];
        __syncthreads();

        if (epi) {
            const int dd = (tid >> 6) & 3;
            float z[4];
#pragma unroll
            for (int g = 0; g < 4; ++g) {
                const int r = ((dd * 4 + g) << 3);
                float s = 0.f;
#pragma unroll
                for (int kk = 0; kk < 8; ++kk) s += red[r + kk][eb];
                z[g] = s + xzv[g];
            }
            float ig = 1.f / (1.f + __expf(-z[0]));
            float fg = 1.f / (1.f + __expf(-z[1]));
            float gg = tanhf(z[2]);
            float og = 1.f / (1.f + __expf(-z[3]));
            float c_new = fg * c_reg + ig * gg;
            float h_new = og * tanhf(c_new);
            bool msk = t < len_b;
            float h_out = msk ? h_new : hp_epi;
            c_reg = msk ? c_new : c_reg;
            stg_llc(hn + ed * 64 + eb, h_out);                       // LLC write-through
            hc_out[(size_t)tl * (D_ * 64) + ed * 64 + eb] = h_out;   // plain (next kernel)
        }

        if (tl != TC - 1)
            grid_barrier(bar, bar_base + (unsigned)tl + 1u);
    }
    if (epi) c_st[ed * 64 + eb] = c_reg;    // persist c for next chunk
}

// ---------------------------------------------------------------------------
// Transpose chunk h1c [tl][d][b] -> out [b][t0+tl][d]   (unchanged)
// ---------------------------------------------------------------------------
__global__ __launch_bounds__(256) void transpose_kernel(
    const float* __restrict__ h1c, float* __restrict__ out, int t0)
{
    const int tl   = blockIdx.x;
    const int dblk = blockIdx.y;
    __shared__ float tile[64][65];

    const int r  = threadIdx.x >> 2;
    const int cq = threadIdx.x & 3;

    const float* src = h1c + (size_t)tl * (D_ * 64) + (size_t)(dblk * 64 + r) * 64 + cq * 16;
#pragma unroll
    for (int j = 0; j < 4; ++j) {
        float4 v = *(const float4*)(src + j * 4);
        tile[r][cq * 16 + j * 4 + 0] = v.x;
        tile[r][cq * 16 + j * 4 + 1] = v.y;
        tile[r][cq * 16 + j * 4 + 2] = v.z;
        tile[r][cq * 16 + j * 4 + 3] = v.w;
    }
    __syncthreads();

    float* dst = out + (size_t)r * (U_ * D_) + (size_t)(t0 + tl) * D_ + dblk * 64 + cq * 16;
#pragma unroll
    for (int j = 0; j < 4; ++j) {
        float4 w;
        w.x = tile[cq * 16 + j * 4 + 0][r];
        w.y = tile[cq * 16 + j * 4 + 1][r];
        w.z = tile[cq * 16 + j * 4 + 2][r];
        w.w = tile[cq * 16 + j * 4 + 3][r];
        *(float4*)(dst + j * 4) = w;
    }
}

// ---------------------------------------------------------------------------
extern "C" void kernel_launch(void* const* d_in, const int* in_sizes, int n_in,
                              void* d_out, int out_size, void* d_ws, size_t ws_size,
                              hipStream_t stream)
{
    const int*   targets = (const int*)d_in[0];
    const int*   lens    = (const int*)d_in[1];
    const float* embed   = (const float*)d_in[2];
    const float* W0      = (const float*)d_in[3];
    const float* U0      = (const float*)d_in[4];
    const float* b0      = (const float*)d_in[5];
    const float* W1      = (const float*)d_in[6];
    const float* U1      = (const float*)d_in[7];
    const float* b1      = (const float*)d_in[8];
    float* out = (float*)d_out;
    float* ws  = (float*)d_ws;

    // workspace layout (floats)
    float* xz  = ws;                                   // TC*2560*64 = 10,485,760
    float* h0c = xz  + (size_t)TC * L4_ * 64;          // TC*640*64  =  2,621,440
    float* h1c = h0c + (size_t)TC * D_ * 64;           // TC*640*64
    float* st  = h1c + (size_t)TC * D_ * 64;           // 6 * 40,960 state buffers
    float* h0a = st;
    float* h0b = st + 40960;
    float* c0  = st + 2 * 40960;
    float* h1a = st + 3 * 40960;
    float* h1b = st + 4 * 40960;
    float* c1  = st + 5 * 40960;
    unsigned* bar = (unsigned*)(st + 6 * 40960);       // 512 uints (9 x 128B lines used)
    float* Up0 = st + 6 * 40960 + 512;                 // 640*2560 = 1,638,400
    float* Up1 = Up0 + (size_t)D_ * L4_;               // 640*2560
    // total ~19.25M floats ~= 77 MB (same as round-3 verified layout)

    // zero-init states + barrier words (ws is poisoned before every call)
    hipMemsetAsync(st, 0, (size_t)6 * 40960 * sizeof(float) + 2048, stream);

    // one-time recurrent-weight transpose for both layers
    prep_up_kernel<<<dim3(D_, 2), dim3(256), 0, stream>>>(U0, U1, Up0, Up1);

    const dim3 gemm_grid(TC * 64 / 128, L4_ / 128);    // (32, 20)
    const dim3 blk(256);
    const dim3 blk_seq(512);

    unsigned launch_idx = 0;
    for (int ch = 0; ch < NCH; ++ch) {
        const int t0 = ch * TC;

        // layer 0 input transform: xz = embed[targets] @ W0 + b0
        gemm_kernel<0><<<gemm_grid, blk, 0, stream>>>(embed, targets, W0, b0, xz, E_, t0);

        // layer 0: 64 timesteps in one persistent launch
        lstm_seq_kernel<<<dim3(NBLK), blk_seq, 0, stream>>>(
            xz, Up0, h0a, h0b, c0, lens, h0c, t0, bar, launch_idx * 63u);
        ++launch_idx;

        // layer 1 input transform: xz = h0c @ W1 + b1
        gemm_kernel<1><<<gemm_grid, blk, 0, stream>>>(h0c, targets, W1, b1, xz, D_, t0);

        // layer 1: 64 timesteps in one persistent launch
        lstm_seq_kernel<<<dim3(NBLK), blk_seq, 0, stream>>>(
            xz, Up1, h1a, h1b, c1, lens, h1c, t0, bar, launch_idx * 63u);
        ++launch_idx;

        // emit chunk to output
        transpose_kernel<<<dim3(TC, 10), blk, 0, stream>>>(h1c, out, t0);
    }
}

// Round 6
// 41970.737 us; speedup vs baseline: 13.2155x; 13.2155x over previous
//
#include <hip/hip_runtime.h>
#include <math.h>

// Problem constants
#define B_   64
#define U_   1024
#define E_   512
#define D_   640
#define L4_  2560
#define TC   64          // time-chunk length
#define NCH  16          // number of chunks (TC*NCH == U_)
#define NBLK 160         // persistent blocks (4 d's each); 160 <= 256 CUs -> co-resident
#define SUBQ (NBLK / 8)  // blocks per sub-counter

// ---------------------------------------------------------------------------
// GEMM: C[t][n][b] = bias[n] + sum_k A[m][k] * W[k][n],  m = t*64 + b
// MODE 0: A row m comes from embed[targets[b][t0+t]] (gather), K = 512
// MODE 1: A is h0c with layout [t][k][b] (stride 640*64 per t),  K = 640
// Block tile 128x128, 256 threads, 8x8 per-thread tile, BK=8.  (unchanged)
// ---------------------------------------------------------------------------
template <int MODE>
__global__ __launch_bounds__(256) void gemm_kernel(
    const float* __restrict__ A,        // MODE0: embed [V][E]; MODE1: h0c [TC][640][64]
    const int*   __restrict__ targets,  // [B][U], used in MODE0
    const float* __restrict__ Wm,       // [K][2560]
    const float* __restrict__ bias,     // [2560]
    float* __restrict__ xz,             // [TC][2560][64]
    int K, int t0)
{
    const int tid = threadIdx.x;
    const int m0 = blockIdx.x * 128;
    const int n0 = blockIdx.y * 128;

    __shared__ float As[8][132];
    __shared__ float Bs[8][132];

    float acc[8][8];
#pragma unroll
    for (int i = 0; i < 8; ++i)
#pragma unroll
        for (int j = 0; j < 8; ++j) acc[i][j] = 0.f;

    const float* a_ptr;
    int a_ml = 0, a_kq = 0, a_k = 0;
    if (MODE == 0) {
        a_ml = tid & 127;
        a_kq = (tid >> 7) * 4;
        int m  = m0 + a_ml;
        int b  = m & 63;
        int tl = m >> 6;
        int idx = targets[b * U_ + t0 + tl];
        a_ptr = A + (size_t)idx * E_ + a_kq;
    } else {
        a_k  = tid >> 5;
        a_ml = (tid & 31) * 4;
        int m  = m0 + a_ml;
        int b  = m & 63;
        int tl = m >> 6;
        a_ptr = A + (size_t)tl * (D_ * 64) + (size_t)a_k * 64 + b;
    }
    const int b_k  = tid >> 5;
    const int b_n4 = (tid & 31) * 4;

    const int tx = tid & 15;
    const int ty = tid >> 4;

    for (int k0 = 0; k0 < K; k0 += 8) {
        if (MODE == 0) {
            float4 av = *(const float4*)(a_ptr + k0);
            As[a_kq + 0][a_ml] = av.x;
            As[a_kq + 1][a_ml] = av.y;
            As[a_kq + 2][a_ml] = av.z;
            As[a_kq + 3][a_ml] = av.w;
        } else {
            float4 av = *(const float4*)(a_ptr + (size_t)k0 * 64);
            *(float4*)&As[a_k][a_ml] = av;
        }
        {
            float4 bv = *(const float4*)(Wm + (size_t)(k0 + b_k) * L4_ + n0 + b_n4);
            *(float4*)&Bs[b_k][b_n4] = bv;
        }
        __syncthreads();

#pragma unroll
        for (int k = 0; k < 8; ++k) {
            float af[8], bf[8];
            *(float4*)&af[0] = *(const float4*)&As[k][ty * 8];
            *(float4*)&af[4] = *(const float4*)&As[k][ty * 8 + 4];
            *(float4*)&bf[0] = *(const float4*)&Bs[k][tx * 8];
            *(float4*)&bf[4] = *(const float4*)&Bs[k][tx * 8 + 4];
#pragma unroll
            for (int i = 0; i < 8; ++i)
#pragma unroll
                for (int j = 0; j < 8; ++j) acc[i][j] += af[i] * bf[j];
        }
        __syncthreads();
    }

#pragma unroll
    for (int i = 0; i < 8; ++i) {
        int m  = m0 + ty * 8 + i;
        int tl = m >> 6;
        int b  = m & 63;
        float* outp = xz + (size_t)tl * (L4_ * 64) + b;
#pragma unroll
        for (int j = 0; j < 8; ++j) {
            int n = n0 + tx * 8 + j;
            outp[(size_t)n * 64] = acc[i][j] + bias[n];
        }
    }
}

// ---------------------------------------------------------------------------
// Pre-transpose recurrent weights into per-block-group layout:
//   Upg[g][k][dd][gate] = Uw[k][gate*640 + (g*4+dd)],  g = d>>2, dd = d&3
// One block's slice (g fixed) is 640*16 floats = 40 KB, L2-resident; the seq
// kernel streams it per step via WAVE-UNIFORM s_load (64 B per k) feeding
// v_fmac_f32 v,s,v. No LDS broadcast, no per-lane weight traffic.
// ---------------------------------------------------------------------------
__global__ __launch_bounds__(256) void prep_up_kernel(
    const float* __restrict__ U0w, const float* __restrict__ U1w,
    float* __restrict__ Up0, float* __restrict__ Up1)
{
    const int k = blockIdx.x;                       // 0..639
    const float* Uw = blockIdx.y ? U1w : U0w;
    float*       Up = blockIdx.y ? Up1 : Up0;
    for (int d = threadIdx.x; d < D_; d += 256) {   // coalesced reads over d
        float4 v;
        v.x = Uw[(size_t)k * L4_ + d];
        v.y = Uw[(size_t)k * L4_ + 640  + d];
        v.z = Uw[(size_t)k * L4_ + 1280 + d];
        v.w = Uw[(size_t)k * L4_ + 1920 + d];
        *(float4*)(Up + ((((size_t)(d >> 2) * 640 + k) * 4) + (d & 3)) * 4) = v;
    }
}

// ---------------------------------------------------------------------------
// LLC-coherent scalar access helpers: relaxed agent-scope atomics compile to
// sc1-flagged global_load/store_dword -> bypass the non-coherent per-XCD L2,
// write-through/read-from LLC. Zero cache-maintenance instructions.
// ---------------------------------------------------------------------------
__device__ __forceinline__ float ldg_llc(const float* p) {
    return __hip_atomic_load(p, __ATOMIC_RELAXED, __HIP_MEMORY_SCOPE_AGENT);
}
__device__ __forceinline__ void stg_llc(float* p, float v) {
    __hip_atomic_store(p, v, __ATOMIC_RELAXED, __HIP_MEMORY_SCOPE_AGENT);
}

// ---------------------------------------------------------------------------
// Two-level, monotonic (no-reset) grid barrier. All counters relaxed.
// Proven correct+fast in round 3 (800us dispatches, no outliers).
// ---------------------------------------------------------------------------
__device__ __forceinline__ void grid_barrier(unsigned* bar, unsigned done)
{
    asm volatile("s_waitcnt vmcnt(0)" ::: "memory");
    __syncthreads();
    if (threadIdx.x == 0) {
        unsigned* sub    = bar + ((blockIdx.x & 7) << 5);   // 128B-separated lines
        unsigned* master = bar + (8 << 5);
        unsigned a = __hip_atomic_fetch_add(sub, 1u, __ATOMIC_RELAXED, __HIP_MEMORY_SCOPE_AGENT);
        if (a == done * SUBQ - 1u)
            __hip_atomic_fetch_add(master, 1u, __ATOMIC_RELAXED, __HIP_MEMORY_SCOPE_AGENT);
        const unsigned tgt = done * 8u;
        while (__hip_atomic_load(master, __ATOMIC_RELAXED, __HIP_MEMORY_SCOPE_AGENT) < tgt)
            __builtin_amdgcn_s_sleep(1);
    }
    __syncthreads();
}

// ---------------------------------------------------------------------------
// Persistent LSTM sequence kernel: TC=64 timesteps in ONE launch.
// Round-3 verified skeleton (256 thr, 4 waves, 16-deep double-buffered sc1
// h loads, 184 VGPR no-spill) with ONE change: the weight operand streams
// through the SCALAR pipe instead of LDS broadcast.
//   - wk base is made provably wave-uniform via readfirstlane(ks) -> the
//     16 consecutive gate-weights of each k become s_load_dwordx16 from the
//     L2-resident 40 KB slice; FMAs are v_fmac_f32 v,s,v. (K$ coherence is
//     safe: Upg is written by a PRIOR dispatch; caches invalidate at
//     dispatch boundaries.)
//   - removes the 2560 broadcast ds_read_b128 per CU-step that capped round 3
//     at 12.5 us/step (model: 2560x12cyc = 30.7k cyc == measured; VALUBusy
//     18% == 5120/30700).
// Round-4's failure (hv[80] scratch spill -> 29 GB HBM/dispatch) is avoided:
// per-thread arrays stay at round-3 sizes (hvA/hvB[16], p[16]).
// ---------------------------------------------------------------------------
__global__ __launch_bounds__(256) void lstm_seq_kernel(
    const float* __restrict__ xz,      // [TC][2560][64]
    const float* __restrict__ Upg,     // [160][640][4][4] pre-transposed
    float* __restrict__ hA,            // [640][64] ping
    float* __restrict__ hB,            // [640][64] pong
    float* __restrict__ c_st,          // [640][64]
    const int* __restrict__ lens,      // [64]
    float* __restrict__ hc_out,        // [TC][640][64]
    int t0,
    unsigned* __restrict__ bar,
    unsigned bar_base)                 // absolute barrier index base for this launch
{
    const int tid = threadIdx.x;
    const int d0  = blockIdx.x * 4;
    const int b   = tid & 63;
    const int ks  = tid >> 6;            // 0..3
    const int kbeg = ks * 160;

    __shared__ float red[64][64];        // 16 KB: [ (i=dd*4+gate)*4 + ks ][ b ]

    // provably wave-uniform weight base -> scalar (s_load) path
    const int uks = __builtin_amdgcn_readfirstlane(ks);
    const float* __restrict__ wk = Upg + (size_t)blockIdx.x * (640 * 16)
                                       + (size_t)uks * (160 * 16);

    // epilogue-private state: all 256 threads own one (d,b) cell
    const int ed = d0 + (tid >> 6);
    const int eb = tid & 63;
    float c_reg   = c_st[ed * 64 + eb];   // c never crosses blocks
    const int len_b = lens[eb];

#define LOADB(HV, KK)                                                       \
    _Pragma("unroll")                                                       \
    for (int j = 0; j < 16; ++j)                                            \
        HV[j] = ldg_llc(hpb + (((KK) + j) << 6));

    // weights via wave-uniform scalar loads: wk[kl*16 + i] (64 B per kl)
#define FMAS(HV, KL)                                                        \
    _Pragma("unroll")                                                       \
    for (int j = 0; j < 16; ++j) {                                          \
        const float hvv = HV[j];                                            \
        const float* wp = wk + ((KL) + j) * 16;                             \
        _Pragma("unroll")                                                   \
        for (int i = 0; i < 16; ++i)                                        \
            p[i] += wp[i] * hvv;                                            \
    }

    for (int tl = 0; tl < TC; ++tl) {
        const int t = t0 + tl;
        const float* hp = (t & 1) ? hB : hA;    // same parity rule as before
        float*       hn = (t & 1) ? hA : hB;

        // prefetch epilogue operands early -> latency hidden under k-loop
        float xzv[4];
        {
            const float* xzp = xz + (size_t)tl * (L4_ * 64) + eb;
#pragma unroll
            for (int g = 0; g < 4; ++g)
                xzv[g] = xzp[(size_t)(ed + 640 * g) * 64];
        }
        const float hp_epi = ldg_llc(hp + ed * 64 + eb);

        float p[16];
#pragma unroll
        for (int i = 0; i < 16; ++i) p[i] = 0.f;

        const float* hpb = hp + b;
        float hvA[16], hvB[16];
        LOADB(hvA, kbeg)
        for (int i = 0; i < 5; ++i) {           // rolled: bounds I$ footprint
            const int kk = kbeg + i * 32;       // absolute k for h loads
            const int kl = i * 32;              // local k for weight slice
            LOADB(hvB, kk + 16)
            FMAS(hvA, kl)
            if (i < 4) { LOADB(hvA, kk + 32) }
            FMAS(hvB, kl + 16)
        }

#pragma unroll
        for (int i = 0; i < 16; ++i) red[(i << 2) | ks][b] = p[i];
        __syncthreads();

        {
            const int dd = tid >> 6;
            float z[4];
#pragma unroll
            for (int g = 0; g < 4; ++g) {
                const int r = ((dd * 4 + g) << 2);
                z[g] = red[r][eb] + red[r + 1][eb] + red[r + 2][eb] + red[r + 3][eb]
                     + xzv[g];
            }
            float ig = 1.f / (1.f + __expf(-z[0]));
            float fg = 1.f / (1.f + __expf(-z[1]));
            float gg = tanhf(z[2]);
            float og = 1.f / (1.f + __expf(-z[3]));
            float c_new = fg * c_reg + ig * gg;
            float h_new = og * tanhf(c_new);
            bool msk = t < len_b;
            float h_out = msk ? h_new : hp_epi;
            c_reg = msk ? c_new : c_reg;
            stg_llc(hn + ed * 64 + eb, h_out);                       // LLC write-through
            hc_out[(size_t)tl * (D_ * 64) + ed * 64 + eb] = h_out;   // plain (next kernel)
        }

        if (tl != TC - 1)
            grid_barrier(bar, bar_base + (unsigned)tl + 1u);
    }
    c_st[ed * 64 + eb] = c_reg;             // persist c for next chunk
#undef LOADB
#undef FMAS
}

// ---------------------------------------------------------------------------
// Transpose chunk h1c [tl][d][b] -> out [b][t0+tl][d]   (unchanged)
// ---------------------------------------------------------------------------
__global__ __launch_bounds__(256) void transpose_kernel(
    const float* __restrict__ h1c, float* __restrict__ out, int t0)
{
    const int tl   = blockIdx.x;
    const int dblk = blockIdx.y;
    __shared__ float tile[64][65];

    const int r  = threadIdx.x >> 2;
    const int cq = threadIdx.x & 3;

    const float* src = h1c + (size_t)tl * (D_ * 64) + (size_t)(dblk * 64 + r) * 64 + cq * 16;
#pragma unroll
    for (int j = 0; j < 4; ++j) {
        float4 v = *(const float4*)(src + j * 4);
        tile[r][cq * 16 + j * 4 + 0] = v.x;
        tile[r][cq * 16 + j * 4 + 1] = v.y;
        tile[r][cq * 16 + j * 4 + 2] = v.z;
        tile[r][cq * 16 + j * 4 + 3] = v.w;
    }
    __syncthreads();

    float* dst = out + (size_t)r * (U_ * D_) + (size_t)(t0 + tl) * D_ + dblk * 64 + cq * 16;
#pragma unroll
    for (int j = 0; j < 4; ++j) {
        float4 w;
        w.x = tile[cq * 16 + j * 4 + 0][r];
        w.y = tile[cq * 16 + j * 4 + 1][r];
        w.z = tile[cq * 16 + j * 4 + 2][r];
        w.w = tile[cq * 16 + j * 4 + 3][r];
        *(float4*)(dst + j * 4) = w;
    }
}

// ---------------------------------------------------------------------------
extern "C" void kernel_launch(void* const* d_in, const int* in_sizes, int n_in,
                              void* d_out, int out_size, void* d_ws, size_t ws_size,
                              hipStream_t stream)
{
    const int*   targets = (const int*)d_in[0];
    const int*   lens    = (const int*)d_in[1];
    const float* embed   = (const float*)d_in[2];
    const float* W0      = (const float*)d_in[3];
    const float* U0      = (const float*)d_in[4];
    const float* b0      = (const float*)d_in[5];
    const float* W1      = (const float*)d_in[6];
    const float* U1      = (const float*)d_in[7];
    const float* b1      = (const float*)d_in[8];
    float* out = (float*)d_out;
    float* ws  = (float*)d_ws;

    // workspace layout (floats)
    float* xz  = ws;                                   // TC*2560*64 = 10,485,760
    float* h0c = xz  + (size_t)TC * L4_ * 64;          // TC*640*64  =  2,621,440
    float* h1c = h0c + (size_t)TC * D_ * 64;           // TC*640*64
    float* st  = h1c + (size_t)TC * D_ * 64;           // 6 * 40,960 state buffers
    float* h0a = st;
    float* h0b = st + 40960;
    float* c0  = st + 2 * 40960;
    float* h1a = st + 3 * 40960;
    float* h1b = st + 4 * 40960;
    float* c1  = st + 5 * 40960;
    unsigned* bar = (unsigned*)(st + 6 * 40960);       // 512 uints (9 x 128B lines used)
    float* Up0 = st + 6 * 40960 + 512;                 // 640*2560 = 1,638,400 (64B-aligned)
    float* Up1 = Up0 + (size_t)D_ * L4_;               // 640*2560
    // total ~19.25M floats ~= 77 MB (same as round-3 verified layout)

    // zero-init states + barrier words (ws is poisoned before every call)
    hipMemsetAsync(st, 0, (size_t)6 * 40960 * sizeof(float) + 2048, stream);

    // one-time recurrent-weight transpose for both layers
    prep_up_kernel<<<dim3(D_, 2), dim3(256), 0, stream>>>(U0, U1, Up0, Up1);

    const dim3 gemm_grid(TC * 64 / 128, L4_ / 128);    // (32, 20)
    const dim3 blk(256);

    unsigned launch_idx = 0;
    for (int ch = 0; ch < NCH; ++ch) {
        const int t0 = ch * TC;

        // layer 0 input transform: xz = embed[targets] @ W0 + b0
        gemm_kernel<0><<<gemm_grid, blk, 0, stream>>>(embed, targets, W0, b0, xz, E_, t0);

        // layer 0: 64 timesteps in one persistent launch
        lstm_seq_kernel<<<dim3(NBLK), blk, 0, stream>>>(
            xz, Up0, h0a, h0b, c0, lens, h0c, t0, bar, launch_idx * 63u);
        ++launch_idx;

        // layer 1 input transform: xz = h0c @ W1 + b1
        gemm_kernel<1><<<gemm_grid, blk, 0, stream>>>(h0c, targets, W1, b1, xz, D_, t0);

        // layer 1: 64 timesteps in one persistent launch
        lstm_seq_kernel<<<dim3(NBLK), blk, 0, stream>>>(
            xz, Up1, h1a, h1b, c1, lens, h1c, t0, bar, launch_idx * 63u);
        ++launch_idx;

        // emit chunk to output
        transpose_kernel<<<dim3(TC, 10), blk, 0, stream>>>(h1c, out, t0);
    }
}

// Round 7
// 25104.366 us; speedup vs baseline: 22.0943x; 1.6719x over previous
//
#include <hip/hip_runtime.h>
#include <math.h>

// Problem constants
#define B_   64
#define U_   1024
#define E_   512
#define D_   640
#define L4_  2560
#define TC   64          // time-chunk length
#define NCH  16          // number of chunks (TC*NCH == U_)
#define NBLK 160         // persistent blocks (4 d's each); 160 <= 256 CUs -> co-resident
#define SUBQ (NBLK / 8)  // blocks per sub-counter

// ---------------------------------------------------------------------------
// GEMM: C[t][n][b] = bias[n] + sum_k A[m][k] * W[k][n],  m = t*64 + b
// (unchanged, harness-verified)
// ---------------------------------------------------------------------------
template <int MODE>
__global__ __launch_bounds__(256) void gemm_kernel(
    const float* __restrict__ A,        // MODE0: embed [V][E]; MODE1: h0c [TC][640][64]
    const int*   __restrict__ targets,  // [B][U], used in MODE0
    const float* __restrict__ Wm,       // [K][2560]
    const float* __restrict__ bias,     // [2560]
    float* __restrict__ xz,             // [TC][2560][64]
    int K, int t0)
{
    const int tid = threadIdx.x;
    const int m0 = blockIdx.x * 128;
    const int n0 = blockIdx.y * 128;

    __shared__ float As[8][132];
    __shared__ float Bs[8][132];

    float acc[8][8];
#pragma unroll
    for (int i = 0; i < 8; ++i)
#pragma unroll
        for (int j = 0; j < 8; ++j) acc[i][j] = 0.f;

    const float* a_ptr;
    int a_ml = 0, a_kq = 0, a_k = 0;
    if (MODE == 0) {
        a_ml = tid & 127;
        a_kq = (tid >> 7) * 4;
        int m  = m0 + a_ml;
        int b  = m & 63;
        int tl = m >> 6;
        int idx = targets[b * U_ + t0 + tl];
        a_ptr = A + (size_t)idx * E_ + a_kq;
    } else {
        a_k  = tid >> 5;
        a_ml = (tid & 31) * 4;
        int m  = m0 + a_ml;
        int b  = m & 63;
        int tl = m >> 6;
        a_ptr = A + (size_t)tl * (D_ * 64) + (size_t)a_k * 64 + b;
    }
    const int b_k  = tid >> 5;
    const int b_n4 = (tid & 31) * 4;

    const int tx = tid & 15;
    const int ty = tid >> 4;

    for (int k0 = 0; k0 < K; k0 += 8) {
        if (MODE == 0) {
            float4 av = *(const float4*)(a_ptr + k0);
            As[a_kq + 0][a_ml] = av.x;
            As[a_kq + 1][a_ml] = av.y;
            As[a_kq + 2][a_ml] = av.z;
            As[a_kq + 3][a_ml] = av.w;
        } else {
            float4 av = *(const float4*)(a_ptr + (size_t)k0 * 64);
            *(float4*)&As[a_k][a_ml] = av;
        }
        {
            float4 bv = *(const float4*)(Wm + (size_t)(k0 + b_k) * L4_ + n0 + b_n4);
            *(float4*)&Bs[b_k][b_n4] = bv;
        }
        __syncthreads();

#pragma unroll
        for (int k = 0; k < 8; ++k) {
            float af[8], bf[8];
            *(float4*)&af[0] = *(const float4*)&As[k][ty * 8];
            *(float4*)&af[4] = *(const float4*)&As[k][ty * 8 + 4];
            *(float4*)&bf[0] = *(const float4*)&Bs[k][tx * 8];
            *(float4*)&bf[4] = *(const float4*)&Bs[k][tx * 8 + 4];
#pragma unroll
            for (int i = 0; i < 8; ++i)
#pragma unroll
                for (int j = 0; j < 8; ++j) acc[i][j] += af[i] * bf[j];
        }
        __syncthreads();
    }

#pragma unroll
    for (int i = 0; i < 8; ++i) {
        int m  = m0 + ty * 8 + i;
        int tl = m >> 6;
        int b  = m & 63;
        float* outp = xz + (size_t)tl * (L4_ * 64) + b;
#pragma unroll
        for (int j = 0; j < 8; ++j) {
            int n = n0 + tx * 8 + j;
            outp[(size_t)n * 64] = acc[i][j] + bias[n];
        }
    }
}

// ---------------------------------------------------------------------------
// Pre-transpose recurrent weights, N-MAJOR per block:
//   Up[g][n16][k] = Uw[k][gate*640 + (g*4+dd)],  n16 = dd*4 + gate
// Block g's slice is 16 rows x 640 k = 40 KB contiguous; seq kernel stages it
// to LDS once and reads it PER-LANE (each lane a different n-row) -> no
// broadcast wall (round 3: 2560 bcast b128 x 12cyc = 12.5us/step) and no
// scalar-pipe wall (round 6: K$ thrash, 18.4us/step).
// ---------------------------------------------------------------------------
__global__ __launch_bounds__(256) void prep_up_kernel(
    const float* __restrict__ U0w, const float* __restrict__ U1w,
    float* __restrict__ Up0, float* __restrict__ Up1)
{
    const int k = blockIdx.x;                       // 0..639
    const float* Uw = blockIdx.y ? U1w : U0w;
    float*       Up = blockIdx.y ? Up1 : Up0;
    for (int d = threadIdx.x; d < D_; d += 256) {   // coalesced reads over d
        const int g  = d >> 2;
        const int dd = d & 3;
#pragma unroll
        for (int gate = 0; gate < 4; ++gate) {
            float v = Uw[(size_t)k * L4_ + gate * 640 + d];
            Up[((size_t)g * 16 + dd * 4 + gate) * 640 + k] = v;
        }
    }
}

// ---------------------------------------------------------------------------
// LLC-coherent access helpers (relaxed agent-scope atomics -> sc1 loads/
// stores: bypass non-coherent per-XCD L2, zero cache-maintenance insts).
// 8-byte variant for the h[k][b0..b1] pair loads (native global_load_dwordx2).
// ---------------------------------------------------------------------------
__device__ __forceinline__ float ldg_llc(const float* p) {
    return __hip_atomic_load(p, __ATOMIC_RELAXED, __HIP_MEMORY_SCOPE_AGENT);
}
__device__ __forceinline__ unsigned long long ldg_llc2(const unsigned long long* p) {
    return __hip_atomic_load(p, __ATOMIC_RELAXED, __HIP_MEMORY_SCOPE_AGENT);
}
__device__ __forceinline__ void stg_llc(float* p, float v) {
    __hip_atomic_store(p, v, __ATOMIC_RELAXED, __HIP_MEMORY_SCOPE_AGENT);
}

// ---------------------------------------------------------------------------
// Two-level, monotonic (no-reset) grid barrier. Proven in rounds 3/6.
// ---------------------------------------------------------------------------
__device__ __forceinline__ void grid_barrier(unsigned* bar, unsigned done)
{
    asm volatile("s_waitcnt vmcnt(0)" ::: "memory");
    __syncthreads();
    if (threadIdx.x == 0) {
        unsigned* sub    = bar + ((blockIdx.x & 7) << 5);   // 128B-separated lines
        unsigned* master = bar + (8 << 5);
        unsigned a = __hip_atomic_fetch_add(sub, 1u, __ATOMIC_RELAXED, __HIP_MEMORY_SCOPE_AGENT);
        if (a == done * SUBQ - 1u)
            __hip_atomic_fetch_add(master, 1u, __ATOMIC_RELAXED, __HIP_MEMORY_SCOPE_AGENT);
        const unsigned tgt = done * 8u;
        while (__hip_atomic_load(master, __ATOMIC_RELAXED, __HIP_MEMORY_SCOPE_AGENT) < tgt)
            __builtin_amdgcn_s_sleep(1);
    }
    __syncthreads();
}

// ---------------------------------------------------------------------------
// Persistent LSTM sequence kernel, SWAPPED operand geometry.
// Grid: 160 blocks x 256 threads (4 waves); block owns dims d0..d0+3
// (16 gate-rows n16 = dd*4+gate). Wave ks = k-slice of 160 (as round 3).
// Lane layout: n_grp = lane>>5 (2 groups), b_grp = lane&31 (32 groups).
// Thread tile: 8 n-rows (n_grp*8..+7) x 2 batch cols (b_grp*2..+1), 16 acc.
// Per 4k: 8 per-lane ds_read_b128 of U rows (2 distinct addrs/inst -> 2-way
// broadcast = FREE per m136) + 4 dwordx2 LLC h loads; 64 FMA. Per step/wave:
// 320 DS (3840 cyc) < 2560 FMA (5120 cyc) -> VALU-bound (round 3 proved
// DS/VALU overlap: total == max). U double-buffered @4k (hides LDS lat),
// h double-buffered @16k (~700cyc ahead, hides LLC lat). All static idx.
// ---------------------------------------------------------------------------
__global__ __launch_bounds__(256) void lstm_seq_kernel(
    const float* __restrict__ xz,      // [TC][2560][64]
    const float* __restrict__ Upg,     // [160][16][640] pre-transposed (n-major)
    float* __restrict__ hA,            // [640][64] ping
    float* __restrict__ hB,            // [640][64] pong
    float* __restrict__ c_st,          // [640][64]
    const int* __restrict__ lens,      // [64]
    float* __restrict__ hc_out,        // [TC][640][64]
    int t0,
    unsigned* __restrict__ bar,
    unsigned bar_base)
{
    const int tid  = threadIdx.x;
    const int d0   = blockIdx.x * 4;
    const int ks   = tid >> 6;               // 0..3 (wave = k-slice)
    const int kbeg = ks * 160;
    const int lane   = tid & 63;
    const int n_base = (lane >> 5) * 8;      // 0 or 8
    const int b_grp  = lane & 31;            // 0..31
    const int b0     = b_grp * 2;

    __shared__ float U_lds[16 * 640];        // 40 KB, rows n16, k-fast
    __shared__ float red[64][64];            // 16 KB: [n16*4 + ks][b]

    // stage this block's U slice to LDS once (contiguous float4 copy)
    {
        const float* upg = Upg + (size_t)blockIdx.x * (640 * 16);
#pragma unroll
        for (int it = 0; it < 10; ++it) {
            const int e = (it * 256 + tid) * 4;
            *(float4*)&U_lds[e] = *(const float4*)(upg + e);
        }
    }

    // epilogue-private state: all 256 threads own one (d,b) cell
    const int ed = d0 + (tid >> 6);
    const int eb = tid & 63;
    float c_reg   = c_st[ed * 64 + eb];
    const int len_b = lens[eb];

    __syncthreads();                         // U_lds ready

    float acc[16];                           // [i-row 0..7][j-col 0..1]
    unsigned long long HAb[16], HBb[16];     // h: 16 k's x (2 b) each
    float UAb[32], UBb[32];                  // U: 8 rows x 4 k's each

#define HLOADB(HH, KK)                                                      \
    _Pragma("unroll")                                                       \
    for (int j = 0; j < 16; ++j)                                            \
        HH[j] = ldg_llc2(hull + ((KK) + j) * 32 + b_grp);

#define ULOADB(UU, KK)                                                      \
    _Pragma("unroll")                                                       \
    for (int i = 0; i < 8; ++i)                                             \
        *(float4*)&UU[i * 4] =                                              \
            *(const float4*)&U_lds[(n_base + i) * 640 + kbeg + (KK)];

#define FMAS(HH, S, UU)                                                     \
    _Pragma("unroll")                                                       \
    for (int jk = 0; jk < 4; ++jk) {                                        \
        const unsigned long long hu = HH[(S) * 4 + jk];                     \
        const float hlo = __uint_as_float((unsigned)hu);                    \
        const float hhi = __uint_as_float((unsigned)(hu >> 32));            \
        _Pragma("unroll")                                                   \
        for (int i = 0; i < 8; ++i) {                                       \
            const float uv = UU[i * 4 + jk];                                \
            acc[i * 2 + 0] += uv * hlo;                                     \
            acc[i * 2 + 1] += uv * hhi;                                     \
        }                                                                   \
    }

#pragma unroll 1
    for (int tl = 0; tl < TC; ++tl) {
        const int t = t0 + tl;
        const float* hp = (t & 1) ? hB : hA;
        float*       hn = (t & 1) ? hA : hB;

        // prefetch epilogue operands early -> latency hidden under k-loop
        float xzv[4];
        {
            const float* xzp = xz + (size_t)tl * (L4_ * 64) + eb;
#pragma unroll
            for (int g = 0; g < 4; ++g)
                xzv[g] = xzp[(size_t)(ed + 640 * g) * 64];
        }
        const float hp_epi = ldg_llc(hp + ed * 64 + eb);

#pragma unroll
        for (int i = 0; i < 16; ++i) acc[i] = 0.f;

        const unsigned long long* hull =
            (const unsigned long long*)hp + (size_t)kbeg * 32;

        HLOADB(HAb, 0)
        ULOADB(UAb, 0)
#pragma unroll
        for (int tt = 0; tt < 5; ++tt) {
            const int kb = tt * 32;
            HLOADB(HBb, kb + 16)
            ULOADB(UBb, kb + 4);   FMAS(HAb, 0, UAb)
            ULOADB(UAb, kb + 8);   FMAS(HAb, 1, UBb)
            ULOADB(UBb, kb + 12);  FMAS(HAb, 2, UAb)
            ULOADB(UAb, kb + 16);  FMAS(HAb, 3, UBb)
            if (tt < 4) { HLOADB(HAb, kb + 32) }
            ULOADB(UBb, kb + 20);  FMAS(HBb, 0, UAb)
            ULOADB(UAb, kb + 24);  FMAS(HBb, 1, UBb)
            ULOADB(UBb, kb + 28);  FMAS(HBb, 2, UAb)
            if (tt < 4) { ULOADB(UAb, kb + 32) }
            FMAS(HBb, 3, UBb)
        }

        // partials -> LDS (float2 per row; 2-to-4-way conflicts, negligible)
#pragma unroll
        for (int i = 0; i < 8; ++i)
            *(float2*)&red[((n_base + i) << 2) | ks][b0] =
                make_float2(acc[i * 2], acc[i * 2 + 1]);
        __syncthreads();

        {
            const int dd = tid >> 6;
            float z[4];
#pragma unroll
            for (int g = 0; g < 4; ++g) {
                const int r = ((dd * 4 + g) << 2);
                z[g] = red[r][eb] + red[r + 1][eb] + red[r + 2][eb] + red[r + 3][eb]
                     + xzv[g];
            }
            float ig = 1.f / (1.f + __expf(-z[0]));
            float fg = 1.f / (1.f + __expf(-z[1]));
            float gg = tanhf(z[2]);
            float og = 1.f / (1.f + __expf(-z[3]));
            float c_new = fg * c_reg + ig * gg;
            float h_new = og * tanhf(c_new);
            bool msk = t < len_b;
            float h_out = msk ? h_new : hp_epi;
            c_reg = msk ? c_new : c_reg;
            stg_llc(hn + ed * 64 + eb, h_out);                       // LLC write-through
            hc_out[(size_t)tl * (D_ * 64) + ed * 64 + eb] = h_out;   // plain (next kernel)
        }

        if (tl != TC - 1)
            grid_barrier(bar, bar_base + (unsigned)tl + 1u);
    }
    c_st[ed * 64 + eb] = c_reg;             // persist c for next chunk
#undef HLOADB
#undef ULOADB
#undef FMAS
}

// ---------------------------------------------------------------------------
// Transpose chunk h1c [tl][d][b] -> out [b][t0+tl][d]   (unchanged)
// ---------------------------------------------------------------------------
__global__ __launch_bounds__(256) void transpose_kernel(
    const float* __restrict__ h1c, float* __restrict__ out, int t0)
{
    const int tl   = blockIdx.x;
    const int dblk = blockIdx.y;
    __shared__ float tile[64][65];

    const int r  = threadIdx.x >> 2;
    const int cq = threadIdx.x & 3;

    const float* src = h1c + (size_t)tl * (D_ * 64) + (size_t)(dblk * 64 + r) * 64 + cq * 16;
#pragma unroll
    for (int j = 0; j < 4; ++j) {
        float4 v = *(const float4*)(src + j * 4);
        tile[r][cq * 16 + j * 4 + 0] = v.x;
        tile[r][cq * 16 + j * 4 + 1] = v.y;
        tile[r][cq * 16 + j * 4 + 2] = v.z;
        tile[r][cq * 16 + j * 4 + 3] = v.w;
    }
    __syncthreads();

    float* dst = out + (size_t)r * (U_ * D_) + (size_t)(t0 + tl) * D_ + dblk * 64 + cq * 16;
#pragma unroll
    for (int j = 0; j < 4; ++j) {
        float4 w;
        w.x = tile[cq * 16 + j * 4 + 0][r];
        w.y = tile[cq * 16 + j * 4 + 1][r];
        w.z = tile[cq * 16 + j * 4 + 2][r];
        w.w = tile[cq * 16 + j * 4 + 3][r];
        *(float4*)(dst + j * 4) = w;
    }
}

// ---------------------------------------------------------------------------
extern "C" void kernel_launch(void* const* d_in, const int* in_sizes, int n_in,
                              void* d_out, int out_size, void* d_ws, size_t ws_size,
                              hipStream_t stream)
{
    const int*   targets = (const int*)d_in[0];
    const int*   lens    = (const int*)d_in[1];
    const float* embed   = (const float*)d_in[2];
    const float* W0      = (const float*)d_in[3];
    const float* U0      = (const float*)d_in[4];
    const float* b0      = (const float*)d_in[5];
    const float* W1      = (const float*)d_in[6];
    const float* U1      = (const float*)d_in[7];
    const float* b1      = (const float*)d_in[8];
    float* out = (float*)d_out;
    float* ws  = (float*)d_ws;

    // workspace layout (floats)
    float* xz  = ws;                                   // TC*2560*64 = 10,485,760
    float* h0c = xz  + (size_t)TC * L4_ * 64;          // TC*640*64  =  2,621,440
    float* h1c = h0c + (size_t)TC * D_ * 64;           // TC*640*64
    float* st  = h1c + (size_t)TC * D_ * 64;           // 6 * 40,960 state buffers
    float* h0a = st;
    float* h0b = st + 40960;
    float* c0  = st + 2 * 40960;
    float* h1a = st + 3 * 40960;
    float* h1b = st + 4 * 40960;
    float* c1  = st + 5 * 40960;
    unsigned* bar = (unsigned*)(st + 6 * 40960);       // 512 uints (9 x 128B lines used)
    float* Up0 = st + 6 * 40960 + 512;                 // 640*2560 = 1,638,400 (64B-aligned)
    float* Up1 = Up0 + (size_t)D_ * L4_;               // 640*2560
    // total ~19.25M floats ~= 77 MB (same as verified layout)

    // zero-init states + barrier words (ws is poisoned before every call)
    hipMemsetAsync(st, 0, (size_t)6 * 40960 * sizeof(float) + 2048, stream);

    // one-time recurrent-weight transpose for both layers (n-major layout)
    prep_up_kernel<<<dim3(D_, 2), dim3(256), 0, stream>>>(U0, U1, Up0, Up1);

    const dim3 gemm_grid(TC * 64 / 128, L4_ / 128);    // (32, 20)
    const dim3 blk(256);

    unsigned launch_idx = 0;
    for (int ch = 0; ch < NCH; ++ch) {
        const int t0 = ch * TC;

        // layer 0 input transform: xz = embed[targets] @ W0 + b0
        gemm_kernel<0><<<gemm_grid, blk, 0, stream>>>(embed, targets, W0, b0, xz, E_, t0);

        // layer 0: 64 timesteps in one persistent launch
        lstm_seq_kernel<<<dim3(NBLK), blk, 0, stream>>>(
            xz, Up0, h0a, h0b, c0, lens, h0c, t0, bar, launch_idx * 63u);
        ++launch_idx;

        // layer 1 input transform: xz = h0c @ W1 + b1
        gemm_kernel<1><<<gemm_grid, blk, 0, stream>>>(h0c, targets, W1, b1, xz, D_, t0);

        // layer 1: 64 timesteps in one persistent launch
        lstm_seq_kernel<<<dim3(NBLK), blk, 0, stream>>>(
            xz, Up1, h1a, h1b, c1, lens, h1c, t0, bar, launch_idx * 63u);
        ++launch_idx;

        // emit chunk to output
        transpose_kernel<<<dim3(TC, 10), blk, 0, stream>>>(h1c, out, t0);
    }
}